// Round 1
// baseline (270.935 us; speedup 1.0000x reference)
//
#include <hip/hip_runtime.h>
#include <hip/hip_bf16.h>

#define EMBED 768
#define NHEADS 8
#define HDIM 96
#define SEQ 2048
#define BATCH 4
#define NTOK (BATCH*SEQ)   // 8192
#define QKVN (3*EMBED)     // 2304

typedef __attribute__((ext_vector_type(4))) float f32x4;
typedef __attribute__((ext_vector_type(8))) __bf16 bf16x8;

__device__ __forceinline__ unsigned short f2bf(float f) {
  union { float f; unsigned int u; } c; c.f = f;
  unsigned int u = c.u;
  return (unsigned short)((u + 0x7FFFu + ((u >> 16) & 1u)) >> 16);
}

__device__ __forceinline__ void gload_lds16(const void* g, void* l) {
  __builtin_amdgcn_global_load_lds(
      (const __attribute__((address_space(1))) unsigned int*)g,
      (__attribute__((address_space(3))) unsigned int*)l, 16, 0, 0);
}

// ---------------- cast x -> bf16 ----------------
__global__ __launch_bounds__(256) void cast_x_kernel(const float4* __restrict__ in,
                                                     ushort4* __restrict__ out, int n4) {
  int i = blockIdx.x * 256 + threadIdx.x;
  if (i >= n4) return;
  float4 v = in[i];
  out[i] = make_ushort4(f2bf(v.x), f2bf(v.y), f2bf(v.z), f2bf(v.w));
}

// ---------------- transpose+cast W [R][C] f32 -> [C][R] bf16 ----------------
__global__ __launch_bounds__(256) void transpose_cast_kernel(const float* __restrict__ in,
                                                             unsigned short* __restrict__ out,
                                                             int R, int C) {
  __shared__ float t[32][33];
  int c0 = blockIdx.x * 32, r0 = blockIdx.y * 32;
  int tx = threadIdx.x & 31, ty = threadIdx.x >> 5;  // 32 x 8
  #pragma unroll
  for (int i = 0; i < 32; i += 8)
    t[ty + i][tx] = in[(size_t)(r0 + ty + i) * C + c0 + tx];
  __syncthreads();
  #pragma unroll
  for (int i = 0; i < 32; i += 8)
    out[(size_t)(c0 + ty + i) * R + r0 + tx] = f2bf(t[tx][ty + i]);
}

// ---------------- GEMM: A[M][K] bf16 x B[N][K] bf16 (B pre-transposed) ----------------
// MODE 0: epilogue scatters QKV (Q scaled by 1/sqrt(96), V transposed)
// MODE 1: epilogue adds bias, stores f32 to out
template <int MODE>
__global__ __launch_bounds__(256) void gemm_kernel(
    const unsigned short* __restrict__ A, const unsigned short* __restrict__ B,
    const float* __restrict__ bias, int K,
    unsigned short* __restrict__ Qo, unsigned short* __restrict__ Ko,
    unsigned short* __restrict__ Vt, float* __restrict__ out) {
  __shared__ unsigned short As[128][32];
  __shared__ unsigned short Bs[128][32];
  const int tid = threadIdx.x;
  const int lane = tid & 63, wid = tid >> 6;
  const int wr = wid >> 1, wc = wid & 1;
  const int l15 = lane & 15, l16 = lane >> 4;
  const int m0 = blockIdx.y * 128, n0 = blockIdx.x * 128;

  f32x4 acc[4][4] = {};

  for (int k0 = 0; k0 < K; k0 += 32) {
    __syncthreads();  // previous iteration's readers done
    #pragma unroll
    for (int i = 0; i < 2; i++) {
      int chunk = i * 256 + tid;
      gload_lds16(A + (size_t)(m0 + (chunk >> 2)) * K + k0 + (chunk & 3) * 8,
                  (char*)As + (i * 256 + wid * 64) * 16);
      gload_lds16(B + (size_t)(n0 + (chunk >> 2)) * K + k0 + (chunk & 3) * 8,
                  (char*)Bs + (i * 256 + wid * 64) * 16);
    }
    __syncthreads();  // staging complete (compiler drains vmcnt before barrier)

    bf16x8 af[4], bfr[4];
    #pragma unroll
    for (int mi = 0; mi < 4; mi++)
      af[mi] = *(const bf16x8*)&As[wr * 64 + mi * 16 + l15][l16 * 8];
    #pragma unroll
    for (int ni = 0; ni < 4; ni++)
      bfr[ni] = *(const bf16x8*)&Bs[wc * 64 + ni * 16 + l15][l16 * 8];
    #pragma unroll
    for (int mi = 0; mi < 4; mi++)
      #pragma unroll
      for (int ni = 0; ni < 4; ni++)
        acc[mi][ni] = __builtin_amdgcn_mfma_f32_16x16x32_bf16(af[mi], bfr[ni], acc[mi][ni], 0, 0, 0);
  }

  if (MODE == 0) {
    const float scale = 0.10206207261596575f;  // 1/sqrt(96)
    #pragma unroll
    for (int mi = 0; mi < 4; mi++) {
      #pragma unroll
      for (int ni = 0; ni < 4; ni++) {
        int col = n0 + wc * 64 + ni * 16 + l15;   // 0..2303
        int h = col / 288;
        int rem = col - h * 288;
        int d = rem / 3;
        int which = rem - d * 3;
        float bb = bias[col];
        #pragma unroll
        for (int j = 0; j < 4; j++) {
          int row = m0 + wr * 64 + mi * 16 + l16 * 4 + j;  // token 0..8191
          int bi = row >> 11, nn = row & 2047;
          float v = acc[mi][ni][j] + bb;
          size_t bh = (size_t)(bi * NHEADS + h);
          if (which == 0)      Qo[(bh * SEQ + nn) * HDIM + d] = f2bf(v * scale);
          else if (which == 1) Ko[(bh * SEQ + nn) * HDIM + d] = f2bf(v);
          else                 Vt[(bh * HDIM + d) * SEQ + nn] = f2bf(v);
        }
      }
    }
  } else {
    #pragma unroll
    for (int mi = 0; mi < 4; mi++) {
      #pragma unroll
      for (int ni = 0; ni < 4; ni++) {
        int col = n0 + wc * 64 + ni * 16 + l15;
        float bb = bias[col];
        #pragma unroll
        for (int j = 0; j < 4; j++) {
          int row = m0 + wr * 64 + mi * 16 + l16 * 4 + j;
          out[(size_t)row * EMBED + col] = acc[mi][ni][j] + bb;
        }
      }
    }
  }
}

// ---------------- flash attention ----------------
// Q [B][H][N][96] bf16 (pre-scaled), K [B][H][N][96] bf16, Vt [B][H][96][N] bf16
// Out: attn [B][N][H*96] bf16
__global__ __launch_bounds__(256) void attn_kernel(
    const unsigned short* __restrict__ Q, const unsigned short* __restrict__ Kd,
    const unsigned short* __restrict__ Vt, unsigned short* __restrict__ Oa) {
  __shared__ unsigned short Qs[128][96];    // 24 KB
  __shared__ unsigned short Ks[64][96];     // 12 KB
  __shared__ unsigned short Vs[96][64];     // 12 KB  (V^T tile: [d][k])
  __shared__ unsigned short Ps[4][32][64];  // 16 KB  (per-wave P)

  const int tid = threadIdx.x, lane = tid & 63, wid = tid >> 6;
  const int l15 = lane & 15, l16 = lane >> 4;
  const int bx = blockIdx.x;
  const int qb = bx & 15, bh = bx >> 4;     // bh = bi*8+h
  const int bi = bh >> 3, h = bh & 7;
  const int q0 = qb * 128;

  const unsigned short* Qg = Q + ((size_t)bh * SEQ + q0) * HDIM;
  const unsigned short* Kg = Kd + (size_t)bh * SEQ * HDIM;
  const unsigned short* Vg = Vt + (size_t)bh * HDIM * SEQ;

  // stage Q tile (contiguous 128*96 elems = 1536 x 16B chunks)
  #pragma unroll
  for (int i = 0; i < 6; i++) {
    int chunk = i * 256 + tid;
    gload_lds16(Qg + chunk * 8, (char*)Qs + (i * 256 + wid * 64) * 16);
  }

  f32x4 oacc[2][6] = {};
  float mrow[2][4], lrow[2][4];
  #pragma unroll
  for (int mi = 0; mi < 2; mi++)
    #pragma unroll
    for (int j = 0; j < 4; j++) { mrow[mi][j] = -__builtin_inff(); lrow[mi][j] = 0.f; }

  for (int kb = 0; kb < SEQ / 64; kb++) {
    const int k0 = kb * 64;
    __syncthreads();  // previous K/V readers done (also drains Q staging on kb=0)
    #pragma unroll
    for (int i = 0; i < 3; i++) {  // K tile: contiguous 64*96 = 768 chunks
      int chunk = i * 256 + tid;
      gload_lds16(Kg + (size_t)k0 * HDIM + chunk * 8, (char*)Ks + (i * 256 + wid * 64) * 16);
    }
    #pragma unroll
    for (int i = 0; i < 3; i++) {  // V^T tile: 96 rows x 64 cols, row stride SEQ
      int chunk = i * 256 + tid;
      gload_lds16(Vg + (size_t)(chunk >> 3) * SEQ + k0 + (chunk & 7) * 8,
                  (char*)Vs + (i * 256 + wid * 64) * 16);
    }
    __syncthreads();

    // S = Q K^T for this wave's 32 rows
    f32x4 sacc[2][4] = {};
    #pragma unroll
    for (int ks = 0; ks < 3; ks++) {
      bf16x8 aq[2], bk[4];
      #pragma unroll
      for (int mi = 0; mi < 2; mi++)
        aq[mi] = *(const bf16x8*)&Qs[wid * 32 + mi * 16 + l15][ks * 32 + l16 * 8];
      #pragma unroll
      for (int ni = 0; ni < 4; ni++)
        bk[ni] = *(const bf16x8*)&Ks[ni * 16 + l15][ks * 32 + l16 * 8];
      #pragma unroll
      for (int mi = 0; mi < 2; mi++)
        #pragma unroll
        for (int ni = 0; ni < 4; ni++)
          sacc[mi][ni] = __builtin_amdgcn_mfma_f32_16x16x32_bf16(aq[mi], bk[ni], sacc[mi][ni], 0, 0, 0);
    }

    // online softmax (rows: wid*32 + mi*16 + l16*4 + j; cols: ni*16 + l15)
    #pragma unroll
    for (int mi = 0; mi < 2; mi++) {
      #pragma unroll
      for (int j = 0; j < 4; j++) {
        float v0 = fmaxf(fmaxf(sacc[mi][0][j], sacc[mi][1][j]),
                         fmaxf(sacc[mi][2][j], sacc[mi][3][j]));
        v0 = fmaxf(v0, __shfl_xor(v0, 1));
        v0 = fmaxf(v0, __shfl_xor(v0, 2));
        v0 = fmaxf(v0, __shfl_xor(v0, 4));
        v0 = fmaxf(v0, __shfl_xor(v0, 8));
        float mnew = fmaxf(mrow[mi][j], v0);
        float alpha = __expf(mrow[mi][j] - mnew);
        mrow[mi][j] = mnew;
        float psum = 0.f;
        #pragma unroll
        for (int ni = 0; ni < 4; ni++) {
          float p = __expf(sacc[mi][ni][j] - mnew);
          sacc[mi][ni][j] = p;
          psum += p;
        }
        psum += __shfl_xor(psum, 1);
        psum += __shfl_xor(psum, 2);
        psum += __shfl_xor(psum, 4);
        psum += __shfl_xor(psum, 8);
        lrow[mi][j] = lrow[mi][j] * alpha + psum;
        #pragma unroll
        for (int ni = 0; ni < 6; ni++) oacc[mi][ni][j] *= alpha;
      }
    }

    // P to per-wave LDS (C-layout -> A-layout round trip)
    #pragma unroll
    for (int mi = 0; mi < 2; mi++)
      #pragma unroll
      for (int ni = 0; ni < 4; ni++)
        #pragma unroll
        for (int j = 0; j < 4; j++)
          Ps[wid][mi * 16 + l16 * 4 + j][ni * 16 + l15] = f2bf(sacc[mi][ni][j]);

    // O += P V   (A = P [32 q][64 k], B = V^T rows [96 d][64 k])
    #pragma unroll
    for (int ks = 0; ks < 2; ks++) {
      bf16x8 pa[2], vb[6];
      #pragma unroll
      for (int mi = 0; mi < 2; mi++)
        pa[mi] = *(const bf16x8*)&Ps[wid][mi * 16 + l15][ks * 32 + l16 * 8];
      #pragma unroll
      for (int ni = 0; ni < 6; ni++)
        vb[ni] = *(const bf16x8*)&Vs[ni * 16 + l15][ks * 32 + l16 * 8];
      #pragma unroll
      for (int mi = 0; mi < 2; mi++)
        #pragma unroll
        for (int ni = 0; ni < 6; ni++)
          oacc[mi][ni] = __builtin_amdgcn_mfma_f32_16x16x32_bf16(pa[mi], vb[ni], oacc[mi][ni], 0, 0, 0);
    }
  }

  // epilogue: normalize, write [b][n][h*96+d] bf16
  unsigned short* Og = Oa + ((size_t)bi * SEQ + q0 + wid * 32) * EMBED + h * HDIM;
  #pragma unroll
  for (int mi = 0; mi < 2; mi++)
    #pragma unroll
    for (int ni = 0; ni < 6; ni++)
      #pragma unroll
      for (int j = 0; j < 4; j++) {
        int r = mi * 16 + l16 * 4 + j;
        float v = oacc[mi][ni][j] / lrow[mi][j];
        Og[(size_t)r * EMBED + ni * 16 + l15] = f2bf(v);
      }
}

extern "C" void kernel_launch(void* const* d_in, const int* in_sizes, int n_in,
                              void* d_out, int out_size, void* d_ws, size_t ws_size,
                              hipStream_t stream) {
  const float* x      = (const float*)d_in[0];
  const float* W_qkv  = (const float*)d_in[1];
  const float* b_qkv  = (const float*)d_in[2];
  const float* W_proj = (const float*)d_in[3];
  const float* b_proj = (const float*)d_in[4];
  float* out = (float*)d_out;

  char* ws = (char*)d_ws;
  size_t off = 0;
  auto alloc = [&](size_t bytes) { void* p = ws + off; off += (bytes + 255) & ~(size_t)255; return p; };
  unsigned short* xb  = (unsigned short*)alloc((size_t)NTOK * EMBED * 2);   // 12.6 MB
  unsigned short* WqT = (unsigned short*)alloc((size_t)QKVN * EMBED * 2);   // 3.5 MB
  unsigned short* WpT = (unsigned short*)alloc((size_t)EMBED * EMBED * 2);  // 1.2 MB
  unsigned short* Qb  = (unsigned short*)alloc((size_t)NTOK * EMBED * 2);   // 12.6 MB
  unsigned short* Kb  = (unsigned short*)alloc((size_t)NTOK * EMBED * 2);   // 12.6 MB
  unsigned short* Vtb = (unsigned short*)alloc((size_t)NTOK * EMBED * 2);   // 12.6 MB
  unsigned short* Ob  = (unsigned short*)alloc((size_t)NTOK * EMBED * 2);   // 12.6 MB

  cast_x_kernel<<<dim3(NTOK * EMBED / 4 / 256), dim3(256), 0, stream>>>(
      (const float4*)x, (ushort4*)xb, NTOK * EMBED / 4);
  transpose_cast_kernel<<<dim3(QKVN / 32, EMBED / 32), dim3(256), 0, stream>>>(W_qkv, WqT, EMBED, QKVN);
  transpose_cast_kernel<<<dim3(EMBED / 32, EMBED / 32), dim3(256), 0, stream>>>(W_proj, WpT, EMBED, EMBED);

  gemm_kernel<0><<<dim3(QKVN / 128, NTOK / 128), dim3(256), 0, stream>>>(
      xb, WqT, b_qkv, EMBED, Qb, Kb, Vtb, nullptr);

  attn_kernel<<<dim3(BATCH * NHEADS * (SEQ / 128)), dim3(256), 0, stream>>>(Qb, Kb, Vtb, Ob);

  gemm_kernel<1><<<dim3(EMBED / 128, NTOK / 128), dim3(256), 0, stream>>>(
      Ob, WpT, b_proj, EMBED, nullptr, nullptr, nullptr, out);
}